// Round 2
// 1188.637 us; speedup vs baseline: 1.2550x; 1.2550x over previous
//
#include <hip/hip_runtime.h>
#include <cstdint>
#include <cstddef>

#define K_DIM 4096
#define BM 256
#define BN 256
#define BK 32
#define NTILES (K_DIM / BK)   // 128 K-tiles

typedef __bf16 bf16x8 __attribute__((ext_vector_type(8)));
typedef float  f32x4  __attribute__((ext_vector_type(4)));
typedef unsigned int u32x4 __attribute__((ext_vector_type(4)));

__device__ __forceinline__ unsigned int pack2_bf16_rne(float lo, float hi) {
    unsigned int ulo = __float_as_uint(lo);
    unsigned int uhi = __float_as_uint(hi);
    ulo += 0x7fffu + ((ulo >> 16) & 1u);
    uhi += 0x7fffu + ((uhi >> 16) & 1u);
    return (ulo >> 16) | (uhi & 0xffff0000u);
}

// x: fp32 -> bf16, 8 elems/thread. NT loads: x is read exactly once — keep it
// out of L2/L3 so the bf16 copies we write stay cached for the GEMM.
__global__ void cvt_x_kernel(const float* __restrict__ in,
                             unsigned short* __restrict__ out, size_t n8) {
    size_t i = (size_t)blockIdx.x * blockDim.x + threadIdx.x;
    if (i >= n8) return;
    const f32x4* p = (const f32x4*)in + i * 2;
    f32x4 a = __builtin_nontemporal_load(p);
    f32x4 b = __builtin_nontemporal_load(p + 1);
    u32x4 r;
    r.x = pack2_bf16_rne(a.x, a.y);
    r.y = pack2_bf16_rne(a.z, a.w);
    r.z = pack2_bf16_rne(b.x, b.y);
    r.w = pack2_bf16_rne(b.z, b.w);
    *((u32x4*)out + i) = r;
}

// weight * wscales[row] : fp32 -> bf16, 8 elems/thread (row-uniform per thread)
__global__ void cvt_w_kernel(const float* __restrict__ w,
                             const float* __restrict__ s,
                             unsigned short* __restrict__ out, size_t n8) {
    size_t i = (size_t)blockIdx.x * blockDim.x + threadIdx.x;
    if (i >= n8) return;
    int row = (int)((i * 8) >> 12);  // / K_DIM
    float sc = s[row];
    const f32x4* p = (const f32x4*)w + i * 2;
    f32x4 a = __builtin_nontemporal_load(p);
    f32x4 b = __builtin_nontemporal_load(p + 1);
    u32x4 r;
    r.x = pack2_bf16_rne(a.x * sc, a.y * sc);
    r.y = pack2_bf16_rne(a.z * sc, a.w * sc);
    r.z = pack2_bf16_rne(b.x * sc, b.y * sc);
    r.w = pack2_bf16_rne(b.z * sc, b.w * sc);
    *((u32x4*)out + i) = r;
}

// ---------------------------------------------------------------------------
// 256x256 tile, 8 waves (2M x 4N), BK=32, 4-deep LDS ring (128 KiB),
// 3-tiles-ahead prefetch with counted vmcnt (never 0 in main loop),
// phase-split MFMA clusters under s_setprio, 2-way (free) LDS swizzle.
// C[m,n] = sum_k A[m,k]*B[n,k] + bias[n]; A [M,K], B [N,K] bf16; C [M,N] f32.
//
// Pipeline invariant: at the end of tile t we s_waitcnt vmcnt(8) -> drains
// exactly tile t+1's 4 global_load_lds; tiles t+2,t+3 (8 loads) stay in
// flight across the barrier. Stage(t+3) overwrites ring slot (t-1)&3, whose
// last reads completed before the previous boundary barrier.
// ---------------------------------------------------------------------------
__global__ __launch_bounds__(512, 2)
void gemm_bf16_256(const unsigned short* __restrict__ A,
                   const unsigned short* __restrict__ B,
                   const float* __restrict__ bias,
                   float* __restrict__ C, int M, int N) {
    // 4 ring buffers x (A 256x32 + B 256x32) bf16 = 4 x 32 KiB = 128 KiB
    __shared__ __attribute__((aligned(16))) unsigned short lds[4 * 16384];

    const int t  = threadIdx.x;
    const int l  = t & 63;
    const int w  = t >> 6;     // wave 0..7
    const int wm = w >> 2;     // 0..1 : M half (128 rows)
    const int wn = w & 3;      // 0..3 : N quarter (64 cols)

    const int num_m = M / BM;              // 32
    const int num_n = N / BN;              // 43
    const int nwg   = num_m * num_n;       // 1376

    // bijective XCD swizzle (m204 form; nwg%8==0 here -> simple case)
    int bid = blockIdx.x;
    int nq = nwg >> 3, nr = nwg & 7;
    int xcd = bid & 7, off = bid >> 3;
    int swz = (xcd < nr ? xcd * (nq + 1) : nr * (nq + 1) + (xcd - nr) * nq) + off;

    // grouped mapping: GM=4 block-rows per band sweeping N.
    // One band (4*43 = 172 blocks) == one XCD chunk -> A band L2/L3-local.
    const int GM = 4;
    int wide = GM * num_n;
    int gid = swz / wide;
    int first_m = gid * GM;
    int gsz = min(GM, num_m - first_m);
    int pm = first_m + (swz % gsz);
    int pn = (swz % wide) / gsz;
    const int rowBase = pm * BM;
    const int colBase = pn * BN;

    // ---- staging: thread t covers row (t>>2) of a 128-row round, 16B chunk
    // (t&3). LDS dest stays LINEAR (global_load_lds requirement); the swizzle
    // chunk^((row>>1)&3) is applied on the GLOBAL source (rule 21 / m173).
    const int sRow = t >> 2;                       // 0..127
    const int gck  = (t & 3) ^ ((t >> 3) & 3);     // pre-swizzled source chunk
    const unsigned short* gA0 = A + (size_t)(rowBase + sRow) * K_DIM + gck * 8;
    const unsigned short* gB0 = B + (size_t)(colBase + sRow) * K_DIM + gck * 8;

    // ---- fragment reads: lane l wants row (l&15 within 16), k-chunk (l>>4);
    // read swizzled slot q ^ ((row>>1)&3). Fragment-row bases are multiples
    // of 16, so ((absrow>>1)&3) == ((mn>>1)&3). Bank check: lanes 0..7 of a
    // ds_read_b128 cover all 32 banks exactly once -> conflict-free.
    const int q  = l >> 4;
    const int mn = l & 15;
    const int qp = q ^ ((mn >> 1) & 3);
    const int aBase =        (wm * 128 + mn) * BK + qp * 8;   // ushort idx
    const int bBase = 8192 + (wn *  64 + mn) * BK + qp * 8;   // ushort idx

#define GLDS(gp, lo)                                                          \
    __builtin_amdgcn_global_load_lds(                                         \
        (const __attribute__((address_space(1))) unsigned int*)(gp),          \
        (__attribute__((address_space(3))) unsigned int*)(&lds[lo]), 16, 0, 0)

#define STAGE_A(tt) do { const int _bo = ((tt) & 3) * 16384;                  \
    GLDS(gA0 + (size_t)(tt) * BK,                        _bo +         t * 8);\
    GLDS(gA0 + (size_t)(tt) * BK + (size_t)128 * K_DIM,  _bo + 4096  + t * 8);\
    } while (0)
#define STAGE_B(tt) do { const int _bo = ((tt) & 3) * 16384;                  \
    GLDS(gB0 + (size_t)(tt) * BK,                        _bo + 8192  + t * 8);\
    GLDS(gB0 + (size_t)(tt) * BK + (size_t)128 * K_DIM,  _bo + 12288 + t * 8);\
    } while (0)

    f32x4 acc[8][4];
#pragma unroll
    for (int i = 0; i < 8; i++)
#pragma unroll
        for (int j = 0; j < 4; j++) acc[i][j] = (f32x4){0.f, 0.f, 0.f, 0.f};

    // prologue: stage tiles 0..2 (12 loads), land tile 0, keep 8 in flight
    STAGE_A(0); STAGE_B(0);
    STAGE_A(1); STAGE_B(1);
    STAGE_A(2); STAGE_B(2);
    asm volatile("s_waitcnt vmcnt(8)" ::: "memory");
    __builtin_amdgcn_s_barrier();

    for (int tt = 0; tt < NTILES; ++tt) {
        const int bo = (tt & 3) * 16384;
        bf16x8 aF[4], bF[4];

        // ---- phase 0: B frags + A frags 0..3, prefetch A(t+3), MFMA quad 0 ----
#pragma unroll
        for (int j = 0; j < 4; j++) bF[j] = *(const bf16x8*)&lds[bo + bBase + j * 512];
#pragma unroll
        for (int i = 0; i < 4; i++) aF[i] = *(const bf16x8*)&lds[bo + aBase + i * 512];
        if (tt + 3 < NTILES) STAGE_A(tt + 3);
        __builtin_amdgcn_s_barrier();
        asm volatile("s_waitcnt lgkmcnt(0)" ::: "memory");
        __builtin_amdgcn_sched_barrier(0);
        __builtin_amdgcn_s_setprio(1);
#pragma unroll
        for (int i = 0; i < 4; i++)
#pragma unroll
            for (int j = 0; j < 4; j++)
                acc[i][j] = __builtin_amdgcn_mfma_f32_16x16x32_bf16(aF[i], bF[j], acc[i][j], 0, 0, 0);
        __builtin_amdgcn_s_setprio(0);
        __builtin_amdgcn_s_barrier();

        // ---- phase 1: A frags 4..7, prefetch B(t+3), MFMA quad 1 ----
#pragma unroll
        for (int i = 0; i < 4; i++) aF[i] = *(const bf16x8*)&lds[bo + aBase + (i + 4) * 512];
        if (tt + 3 < NTILES) STAGE_B(tt + 3);
        __builtin_amdgcn_s_barrier();
        asm volatile("s_waitcnt lgkmcnt(0)" ::: "memory");
        __builtin_amdgcn_sched_barrier(0);
        __builtin_amdgcn_s_setprio(1);
#pragma unroll
        for (int i = 0; i < 4; i++)
#pragma unroll
            for (int j = 0; j < 4; j++)
                acc[i + 4][j] = __builtin_amdgcn_mfma_f32_16x16x32_bf16(aF[i], bF[j], acc[i + 4][j], 0, 0, 0);
        __builtin_amdgcn_s_setprio(0);

        // ---- tile boundary: counted drain — tile t+1 lands, t+2/t+3 fly ----
        if (tt + 3 < NTILES)      asm volatile("s_waitcnt vmcnt(8)" ::: "memory");
        else if (tt + 2 < NTILES) asm volatile("s_waitcnt vmcnt(4)" ::: "memory");
        else if (tt + 1 < NTILES) asm volatile("s_waitcnt vmcnt(0)" ::: "memory");
        __builtin_amdgcn_s_barrier();
    }

#undef GLDS
#undef STAGE_A
#undef STAGE_B

    // C/D layout (m89): col = lane&15, row = (lane>>4)*4 + reg.
    // NT stores: C is write-once — keep it out of L2/L3 so A/B panels stay hot.
#pragma unroll
    for (int j = 0; j < 4; j++) {
        const int col = colBase + wn * 64 + j * 16 + mn;
        const float bv = bias[col];
#pragma unroll
        for (int i = 0; i < 8; i++) {
            const int row0 = rowBase + wm * 128 + i * 16 + q * 4;
#pragma unroll
            for (int r = 0; r < 4; r++) {
                __builtin_nontemporal_store(acc[i][j][r] + bv,
                                            &C[(size_t)(row0 + r) * N + col]);
            }
        }
    }
}

// Emergency fallback (slow but correct) if ws can't hold bf16 copies or the
// shape doesn't tile by 256.
__global__ void gemm_f32_fallback(const float* __restrict__ X,
                                  const float* __restrict__ W,
                                  const float* __restrict__ S,
                                  const float* __restrict__ bias,
                                  float* __restrict__ C, int M, int N) {
    __shared__ float sx[16][17];
    __shared__ float sw[16][17];
    int tx = threadIdx.x, ty = threadIdx.y;
    int row = blockIdx.y * 16 + ty;
    int col = blockIdx.x * 16 + tx;
    float acc = 0.f;
    for (int k0 = 0; k0 < K_DIM; k0 += 16) {
        sx[ty][tx] = X[(size_t)row * K_DIM + k0 + tx];
        sw[ty][tx] = W[(size_t)(blockIdx.x * 16 + ty) * K_DIM + k0 + tx];
        __syncthreads();
#pragma unroll
        for (int kk = 0; kk < 16; kk++) acc += sx[ty][kk] * sw[tx][kk];
        __syncthreads();
    }
    C[(size_t)row * N + col] = acc * S[col] + bias[col];
}

extern "C" void kernel_launch(void* const* d_in, const int* in_sizes, int n_in,
                              void* d_out, int out_size, void* d_ws, size_t ws_size,
                              hipStream_t stream) {
    const float* x    = (const float*)d_in[0];  // [B,S,K]
    const float* wgt  = (const float*)d_in[1];  // [N,K]
    const float* wsc  = (const float*)d_in[2];  // [N,1]
    const float* bias = (const float*)d_in[3];  // [1,N]
    float* out = (float*)d_out;                 // [M,N]

    const size_t M = (size_t)in_sizes[0] / K_DIM;  // 8192
    const size_t N = (size_t)in_sizes[2];          // 11008

    const size_t xb_elems = M * K_DIM;
    const size_t wb_elems = N * K_DIM;
    const size_t need = (xb_elems + wb_elems) * sizeof(unsigned short);

    if (ws_size >= need && (M % BM) == 0 && (N % BN) == 0) {
        unsigned short* xb = (unsigned short*)d_ws;
        unsigned short* wb = xb + xb_elems;
        cvt_x_kernel<<<dim3((unsigned)(xb_elems / 8 / 256)), 256, 0, stream>>>(x, xb, xb_elems / 8);
        cvt_w_kernel<<<dim3((unsigned)(wb_elems / 8 / 256)), 256, 0, stream>>>(wgt, wsc, wb, wb_elems / 8);
        const unsigned nblk = (unsigned)((M / BM) * (N / BN));
        gemm_bf16_256<<<dim3(nblk), 512, 0, stream>>>(xb, wb, bias, out, (int)M, (int)N);
    } else {
        gemm_f32_fallback<<<dim3((unsigned)(N / 16), (unsigned)(M / 16)), dim3(16, 16), 0, stream>>>(
            x, wgt, wsc, bias, out, (int)M, (int)N);
    }
}

// Round 3
// 1147.610 us; speedup vs baseline: 1.2999x; 1.0358x over previous
//
#include <hip/hip_runtime.h>
#include <cstdint>
#include <cstddef>

#define K_DIM 4096
#define BM 256
#define BN 256
#define BK 32
#define NTILES (K_DIM / BK)   // 128 K-tiles

typedef __bf16 bf16x8 __attribute__((ext_vector_type(8)));
typedef float  f32x4  __attribute__((ext_vector_type(4)));
typedef unsigned int u32x4 __attribute__((ext_vector_type(4)));

__device__ __forceinline__ unsigned int pack2_bf16_rne(float lo, float hi) {
    unsigned int ulo = __float_as_uint(lo);
    unsigned int uhi = __float_as_uint(hi);
    ulo += 0x7fffu + ((ulo >> 16) & 1u);
    uhi += 0x7fffu + ((uhi >> 16) & 1u);
    return (ulo >> 16) | (uhi & 0xffff0000u);
}

// x: fp32 -> bf16, 8 elems/thread. NT loads: x is read exactly once — keep it
// out of L2/L3 so the bf16 copies we write stay cached for the GEMM.
__global__ void cvt_x_kernel(const float* __restrict__ in,
                             unsigned short* __restrict__ out, size_t n8) {
    size_t i = (size_t)blockIdx.x * blockDim.x + threadIdx.x;
    if (i >= n8) return;
    const f32x4* p = (const f32x4*)in + i * 2;
    f32x4 a = __builtin_nontemporal_load(p);
    f32x4 b = __builtin_nontemporal_load(p + 1);
    u32x4 r;
    r.x = pack2_bf16_rne(a.x, a.y);
    r.y = pack2_bf16_rne(a.z, a.w);
    r.z = pack2_bf16_rne(b.x, b.y);
    r.w = pack2_bf16_rne(b.z, b.w);
    *((u32x4*)out + i) = r;
}

// weight * wscales[row] : fp32 -> bf16, 8 elems/thread (row-uniform per thread)
__global__ void cvt_w_kernel(const float* __restrict__ w,
                             const float* __restrict__ s,
                             unsigned short* __restrict__ out, size_t n8) {
    size_t i = (size_t)blockIdx.x * blockDim.x + threadIdx.x;
    if (i >= n8) return;
    int row = (int)((i * 8) >> 12);  // / K_DIM
    float sc = s[row];
    const f32x4* p = (const f32x4*)w + i * 2;
    f32x4 a = __builtin_nontemporal_load(p);
    f32x4 b = __builtin_nontemporal_load(p + 1);
    u32x4 r;
    r.x = pack2_bf16_rne(a.x * sc, a.y * sc);
    r.y = pack2_bf16_rne(a.z * sc, a.w * sc);
    r.z = pack2_bf16_rne(b.x * sc, b.y * sc);
    r.w = pack2_bf16_rne(b.z * sc, b.w * sc);
    *((u32x4*)out + i) = r;
}

// ---------------------------------------------------------------------------
// 256x256 tile, 8 waves (2M x 4N), BK=32, 4-deep LDS ring (128 KiB),
// 3-tiles-ahead gl_lds prefetch (counted vmcnt) AND register-fragment
// pipelining (counted lgkmcnt, never 0 in the loop): each phase's frags were
// ds_read-issued one phase earlier, so LDS latency hides under the previous
// MFMA cluster. 2 barriers/tile.
//
// Slot protocol: midB(t) = {vmcnt drains tile t+1's gl_lds; barrier} -> all
// reads of slot (t+1)&3 are issued after midB(t). endB(t): all waves' reads
// of slot t&3 completed (counted lgkm waits) -> STAGE(t+3..) issued after
// endB(t) may overwrite slot (t-1)&3 / (t)&3 safely.
// ---------------------------------------------------------------------------
__global__ __launch_bounds__(512, 2)
void gemm_bf16_256(const unsigned short* __restrict__ A,
                   const unsigned short* __restrict__ B,
                   const float* __restrict__ bias,
                   float* __restrict__ C, int M, int N) {
    // 4 ring buffers x (A 256x32 + B 256x32) bf16 = 4 x 32 KiB = 128 KiB
    __shared__ __attribute__((aligned(16))) unsigned short lds[4 * 16384];

    const int t  = threadIdx.x;
    const int l  = t & 63;
    const int w  = t >> 6;     // wave 0..7
    const int wm = w >> 2;     // 0..1 : M half (128 rows)
    const int wn = w & 3;      // 0..3 : N quarter (64 cols)

    const int num_m = M / BM;              // 32
    const int num_n = N / BN;              // 43
    const int nwg   = num_m * num_n;       // 1376

    // bijective XCD swizzle (m204 form)
    int bid = blockIdx.x;
    int nq = nwg >> 3, nr = nwg & 7;
    int xcd = bid & 7, off = bid >> 3;
    int swz = (xcd < nr ? xcd * (nq + 1) : nr * (nq + 1) + (xcd - nr) * nq) + off;

    // grouped mapping: GM=4 block-rows per band sweeping N.
    const int GM = 4;
    int wide = GM * num_n;
    int gid = swz / wide;
    int first_m = gid * GM;
    int gsz = min(GM, num_m - first_m);
    int pm = first_m + (swz % gsz);
    int pn = (swz % wide) / gsz;
    const int rowBase = pm * BM;
    const int colBase = pn * BN;

    // ---- staging: LDS dest LINEAR (gl_lds requirement); swizzle
    // chunk^((row>>1)&3) applied on the GLOBAL source (rule 21 / m173).
    const int sRow = t >> 2;                       // 0..127
    const int gck  = (t & 3) ^ ((t >> 3) & 3);     // pre-swizzled source chunk
    const unsigned short* gA0 = A + (size_t)(rowBase + sRow) * K_DIM + gck * 8;
    const unsigned short* gB0 = B + (size_t)(colBase + sRow) * K_DIM + gck * 8;

    // ---- fragment reads: lane l -> row (l&15), k-chunk (l>>4), swizzled slot
    // q ^ ((mn>>1)&3). Lanes 0..7 of a ds_read_b128 cover all 32 banks once.
    const int q  = l >> 4;
    const int mn = l & 15;
    const int qp = q ^ ((mn >> 1) & 3);
    const int aBase =        (wm * 128 + mn) * BK + qp * 8;   // ushort idx
    const int bBase = 8192 + (wn *  64 + mn) * BK + qp * 8;   // ushort idx

#define GLDS(gp, lo)                                                          \
    __builtin_amdgcn_global_load_lds(                                         \
        (const __attribute__((address_space(1))) unsigned int*)(gp),          \
        (__attribute__((address_space(3))) unsigned int*)(&lds[lo]), 16, 0, 0)

#define STAGE_A(tt) do { const int _bo = ((tt) & 3) * 16384;                  \
    GLDS(gA0 + (size_t)(tt) * BK,                        _bo +         t * 8);\
    GLDS(gA0 + (size_t)(tt) * BK + (size_t)128 * K_DIM,  _bo + 4096  + t * 8);\
    } while (0)
#define STAGE_B(tt) do { const int _bo = ((tt) & 3) * 16384;                  \
    GLDS(gB0 + (size_t)(tt) * BK,                        _bo + 8192  + t * 8);\
    GLDS(gB0 + (size_t)(tt) * BK + (size_t)128 * K_DIM,  _bo + 12288 + t * 8);\
    } while (0)

    f32x4 acc[8][4];
#pragma unroll
    for (int i = 0; i < 8; i++)
#pragma unroll
        for (int j = 0; j < 4; j++) acc[i][j] = (f32x4){0.f, 0.f, 0.f, 0.f};

    bf16x8 aCur[4], aMid[4], bP[4], bQ[4];

    // prologue: stage tiles 0..2 (12 loads), land tile 0, keep 8 in flight,
    // then issue tile-0 frag reads (one-time exposed latency).
    STAGE_A(0); STAGE_B(0);
    STAGE_A(1); STAGE_B(1);
    STAGE_A(2); STAGE_B(2);
    asm volatile("s_waitcnt vmcnt(8)" ::: "memory");
    __builtin_amdgcn_s_barrier();
#pragma unroll
    for (int i = 0; i < 4; i++) aCur[i] = *(const bf16x8*)&lds[aBase + i * 512];
#pragma unroll
    for (int j = 0; j < 4; j++) bP[j]   = *(const bf16x8*)&lds[bBase + j * 512];

    // Per tile: P0 {issue aMid(t); STAGE_A(t+3); lgkm(4) [aCur/bCur ready,
    // aMid flies]; MFMA quad0; vmcnt(drain t+1); barrier} then
    // P1 {issue aCur(t+1)+bNxt(t+1); STAGE_B(t+3); lgkm(8) [aMid ready];
    // MFMA quad1; barrier}.
#define TILE_BODY(tt, bCur, bNxt)                                             \
    {                                                                         \
        const int bo  = ((tt) & 3) * 16384;                                   \
        const int bo1 = (((tt) + 1) & 3) * 16384;                             \
        _Pragma("unroll")                                                     \
        for (int i = 0; i < 4; i++)                                           \
            aMid[i] = *(const bf16x8*)&lds[bo + aBase + (i + 4) * 512];       \
        if ((tt) + 3 < NTILES) STAGE_A((tt) + 3);                             \
        asm volatile("s_waitcnt lgkmcnt(4)" ::: "memory");                    \
        __builtin_amdgcn_sched_barrier(0);                                    \
        __builtin_amdgcn_s_setprio(1);                                        \
        _Pragma("unroll")                                                     \
        for (int i = 0; i < 4; i++)                                           \
            _Pragma("unroll")                                                 \
            for (int j = 0; j < 4; j++)                                       \
                acc[i][j] = __builtin_amdgcn_mfma_f32_16x16x32_bf16(          \
                    aCur[i], bCur[j], acc[i][j], 0, 0, 0);                    \
        __builtin_amdgcn_s_setprio(0);                                        \
        if ((tt) <= NTILES - 4)                                               \
            asm volatile("s_waitcnt vmcnt(6)" ::: "memory");                  \
        else if ((tt) == NTILES - 3)                                          \
            asm volatile("s_waitcnt vmcnt(4)" ::: "memory");                  \
        else                                                                  \
            asm volatile("s_waitcnt vmcnt(0)" ::: "memory");                  \
        __builtin_amdgcn_s_barrier(); /* midB: slot t+1 globally landed */    \
        if ((tt) + 1 < NTILES) {                                              \
            _Pragma("unroll")                                                 \
            for (int i = 0; i < 4; i++)                                       \
                aCur[i] = *(const bf16x8*)&lds[bo1 + aBase + i * 512];        \
            _Pragma("unroll")                                                 \
            for (int j = 0; j < 4; j++)                                       \
                bNxt[j] = *(const bf16x8*)&lds[bo1 + bBase + j * 512];        \
            if ((tt) + 3 < NTILES) STAGE_B((tt) + 3);                         \
            asm volatile("s_waitcnt lgkmcnt(8)" ::: "memory");                \
        } else {                                                              \
            asm volatile("s_waitcnt lgkmcnt(0)" ::: "memory");                \
        }                                                                     \
        __builtin_amdgcn_sched_barrier(0);                                    \
        __builtin_amdgcn_s_setprio(1);                                        \
        _Pragma("unroll")                                                     \
        for (int i = 0; i < 4; i++)                                           \
            _Pragma("unroll")                                                 \
            for (int j = 0; j < 4; j++)                                       \
                acc[i + 4][j] = __builtin_amdgcn_mfma_f32_16x16x32_bf16(      \
                    aMid[i], bCur[j], acc[i + 4][j], 0, 0, 0);                \
        __builtin_amdgcn_s_setprio(0);                                        \
        __builtin_amdgcn_s_barrier(); /* endB: slot t reads retired */        \
    }

    for (int tt = 0; tt < NTILES; tt += 2) {
        TILE_BODY(tt,     bP, bQ);
        TILE_BODY(tt + 1, bQ, bP);
    }

#undef TILE_BODY
#undef GLDS
#undef STAGE_A
#undef STAGE_B

    // C/D layout (m89): col = lane&15, row = (lane>>4)*4 + reg.
    // NT stores: C is write-once — keep it out of L2/L3 so A/B panels stay hot.
#pragma unroll
    for (int j = 0; j < 4; j++) {
        const int col = colBase + wn * 64 + j * 16 + mn;
        const float bv = bias[col];
#pragma unroll
        for (int i = 0; i < 8; i++) {
            const int row0 = rowBase + wm * 128 + i * 16 + q * 4;
#pragma unroll
            for (int r = 0; r < 4; r++) {
                __builtin_nontemporal_store(acc[i][j][r] + bv,
                                            &C[(size_t)(row0 + r) * N + col]);
            }
        }
    }
}

// Emergency fallback (slow but correct) if ws can't hold bf16 copies or the
// shape doesn't tile by 256.
__global__ void gemm_f32_fallback(const float* __restrict__ X,
                                  const float* __restrict__ W,
                                  const float* __restrict__ S,
                                  const float* __restrict__ bias,
                                  float* __restrict__ C, int M, int N) {
    __shared__ float sx[16][17];
    __shared__ float sw[16][17];
    int tx = threadIdx.x, ty = threadIdx.y;
    int row = blockIdx.y * 16 + ty;
    int col = blockIdx.x * 16 + tx;
    float acc = 0.f;
    for (int k0 = 0; k0 < K_DIM; k0 += 16) {
        sx[ty][tx] = X[(size_t)row * K_DIM + k0 + tx];
        sw[ty][tx] = W[(size_t)(blockIdx.x * 16 + ty) * K_DIM + k0 + tx];
        __syncthreads();
#pragma unroll
        for (int kk = 0; kk < 16; kk++) acc += sx[ty][kk] * sw[tx][kk];
        __syncthreads();
    }
    C[(size_t)row * N + col] = acc * S[col] + bias[col];
}

extern "C" void kernel_launch(void* const* d_in, const int* in_sizes, int n_in,
                              void* d_out, int out_size, void* d_ws, size_t ws_size,
                              hipStream_t stream) {
    const float* x    = (const float*)d_in[0];  // [B,S,K]
    const float* wgt  = (const float*)d_in[1];  // [N,K]
    const float* wsc  = (const float*)d_in[2];  // [N,1]
    const float* bias = (const float*)d_in[3];  // [1,N]
    float* out = (float*)d_out;                 // [M,N]

    const size_t M = (size_t)in_sizes[0] / K_DIM;  // 8192
    const size_t N = (size_t)in_sizes[2];          // 11008

    const size_t xb_elems = M * K_DIM;
    const size_t wb_elems = N * K_DIM;
    const size_t need = (xb_elems + wb_elems) * sizeof(unsigned short);

    if (ws_size >= need && (M % BM) == 0 && (N % BN) == 0) {
        unsigned short* xb = (unsigned short*)d_ws;
        unsigned short* wb = xb + xb_elems;
        cvt_x_kernel<<<dim3((unsigned)(xb_elems / 8 / 256)), 256, 0, stream>>>(x, xb, xb_elems / 8);
        cvt_w_kernel<<<dim3((unsigned)(wb_elems / 8 / 256)), 256, 0, stream>>>(wgt, wsc, wb, wb_elems / 8);
        const unsigned nblk = (unsigned)((M / BM) * (N / BN));
        gemm_bf16_256<<<dim3(nblk), 512, 0, stream>>>(xb, wb, bias, out, (int)M, (int)N);
    } else {
        gemm_f32_fallback<<<dim3((unsigned)(N / 16), (unsigned)(M / 16)), dim3(16, 16), 0, stream>>>(
            x, wgt, wsc, bias, out, (int)M, (int)N);
    }
}